// Round 10
// baseline (304.545 us; speedup 1.0000x reference)
//
#include <hip/hip_runtime.h>
#include <math.h>

typedef float fx4 __attribute__((ext_vector_type(4)));
#define TPB   256
#define BB    16
#define CC    64
#define NCHAN (BB * CC)     // 1024 blocks, one per (b,c) channel
#define N4    16384         // fx4 per channel (65536 floats)
#define VPT   (N4 / TPB)    // 64 fx4 per thread = 256 VGPRs of payload

// ---- init: zero the per-channel flags (graph replay re-runs this) ----
__global__ void bitsel_init_kernel(int* __restrict__ flags) {
    flags[threadIdx.x] = 0;   // launched with NCHAN threads
}

// ---- fused kernel: x lives in REGISTERS across the per-batch sync ----
// Phase 1: stream own channel into v[64] regs, reduce sum/sumsq -> part[j],
//          release-store flag[j].
// Sync:    poll the 64 flags of my batch (coalesced, once per kernel),
//          acquire fence. Caches may be invalidated -- payload is in regs.
// Phase 2: redundant head from partials -> (a, sc); quantize regs; nt-store.
__global__ __launch_bounds__(TPB, 4)
void bitsel_fused_kernel(const fx4* __restrict__ x,
                         const float* __restrict__ gf,
                         const float* __restrict__ bits_in,
                         const float* __restrict__ wbits_in,
                         const float* __restrict__ Wl,
                         const float* __restrict__ bl,
                         const float* __restrict__ a1,
                         const float* __restrict__ a2,
                         const float* __restrict__ a3,
                         float* __restrict__ out,
                         fx4* __restrict__ res,
                         int* __restrict__ flags,   // [NCHAN]
                         float* __restrict__ part,  // [NCHAN][2]
                         size_t Ntot) {
    const int j   = blockIdx.x;        // channel index = b*CC + c
    const int tid = threadIdx.x;
    const int b   = j >> 6;            // j / CC
    const int c   = j & 63;            // j % CC

    // ---------- phase 1: load + reduce ----------
    const fx4* p = x + (size_t)j * N4 + tid;
    fx4 v[VPT];
    #pragma unroll
    for (int k = 0; k < VPT; ++k) v[k] = p[k * TPB];

    float sum = 0.f, sq = 0.f;
    #pragma unroll
    for (int k = 0; k < VPT; ++k) {
        fx4 t = v[k];
        sum += (t.x + t.y) + (t.z + t.w);
        sq  += t.x * t.x + t.y * t.y + t.z * t.z + t.w * t.w;
    }
    for (int off = 32; off > 0; off >>= 1) {
        sum += __shfl_down(sum, off);
        sq  += __shfl_down(sq,  off);
    }
    __shared__ float ssum[4], ssq[4];
    if ((tid & 63) == 0) { ssum[tid >> 6] = sum; ssq[tid >> 6] = sq; }
    __syncthreads();
    if (tid == 0) {
        float S  = ssum[0] + ssum[1] + ssum[2] + ssum[3];
        float Qq = ssq[0]  + ssq[1]  + ssq[2]  + ssq[3];
        part[2 * j + 0] = S;
        part[2 * j + 1] = Qq;
        // release orders the partial stores; distinct address per block ->
        // pipelined plain store, no RMW serialization.
        __hip_atomic_store(&flags[j], 1, __ATOMIC_RELEASE, __HIP_MEMORY_SCOPE_AGENT);
    }

    // ---------- sync: wait for my batch's 64 channels (once per kernel) ----
    for (;;) {
        int ok = 1;
        if (tid < CC) {
            ok = __hip_atomic_load(&flags[b * CC + tid], __ATOMIC_RELAXED,
                                   __HIP_MEMORY_SCOPE_AGENT) != 0;
        }
        if (__syncthreads_and(ok)) break;
        __builtin_amdgcn_s_sleep(64);
    }
    __builtin_amdgcn_fence(__ATOMIC_ACQUIRE, "agent");

    // ---------- phase 2: head (redundant per block) ----------
    __shared__ float s_std[CC];
    __shared__ float s_as[2];
    if (tid < CC) {
        float S  = part[2 * (b * CC + tid) + 0];
        float Qq = part[2 * (b * CC + tid) + 1];
        const float N = (float)N4 * 4.f;
        float var = (Qq - S * S / N) / (N - 1.f);
        s_std[tid] = sqrtf(fmaxf(var, 0.f));
    }
    __syncthreads();
    if (tid == 0) {
        const int D = CC + 2;
        float bt[3];
        for (int kk = 0; kk < 3; ++kk) {
            float acc = gf[2 * b] * Wl[kk * D] + gf[2 * b + 1] * Wl[kk * D + 1];
            for (int cc = 0; cc < CC; ++cc) acc += s_std[cc] * Wl[kk * D + 2 + cc];
            bt[kk] = acc + bl[kk];
        }
        int flag = 0; float m = bt[0];
        if (bt[1] > m) { m = bt[1]; flag = 1; }
        if (bt[2] > m) { m = bt[2]; flag = 2; }
        float e0 = expf(bt[0] - m), e1 = expf(bt[1] - m), e2 = expf(bt[2] - m);
        float esum = e0 + e1 + e2;
        float p1 = e0 / esum, p2 = e1 / esum, p3 = e2 / esum;
        float bits_hard = (flag == 0) ? 4.f : (flag == 1) ? 6.f : 8.f;
        float bits_soft = 4.f * p1 + 6.f * p2 + 8.f * p3;
        float bits_out  = (bits_hard - bits_soft) + bits_soft;   // STE fwd value
        float denom     = 4.f * p1 + 6.f * p2 + 8.f * p3;
        float alpha = (flag == 0) ? a1[0] : (flag == 1) ? a2[0] : a3[0];
        float a  = fabsf(alpha);
        float sc = (exp2f(bits_hard - 1.f) - 1.f) / a;
        s_as[0] = a; s_as[1] = sc;
        if (c == 0) {   // one block per batch writes the tiny outputs
            out[2 * b]     = gf[2 * b];
            out[2 * b + 1] = gf[2 * b + 1];
            out[2 * BB + Ntot + b]      = bits_in[b] + bits_out;
            out[2 * BB + Ntot + BB + b] = wbits_in[b] + bits_out / denom;
        }
    }
    __syncthreads();

    // ---------- phase 2b: quantize register-resident payload, nt-store ----
    const float a  = s_as[0];
    const float sc = s_as[1];
    fx4* q = res + (size_t)j * N4 + tid;
    #pragma unroll
    for (int k = 0; k < VPT; ++k) {
        fx4 t = v[k];
        fx4 r;
        r.x = rintf(fminf(fmaxf(t.x, -a), a) * sc) / sc;
        r.y = rintf(fminf(fmaxf(t.y, -a), a) * sc) / sc;
        r.z = rintf(fminf(fmaxf(t.z, -a), a) * sc) / sc;
        r.w = rintf(fminf(fmaxf(t.w, -a), a) * sc) / sc;
        __builtin_nontemporal_store(r, &q[k * TPB]);
    }
}

extern "C" void kernel_launch(void* const* d_in, const int* in_sizes, int n_in,
                              void* d_out, int out_size, void* d_ws, size_t ws_size,
                              hipStream_t stream) {
    const float* x     = (const float*)d_in[0];
    const float* gf    = (const float*)d_in[1];
    const float* bits  = (const float*)d_in[2];
    const float* wbits = (const float*)d_in[3];
    const float* Wl    = (const float*)d_in[4];
    const float* bl    = (const float*)d_in[5];
    const float* a1    = (const float*)d_in[6];
    const float* a2    = (const float*)d_in[7];
    const float* a3    = (const float*)d_in[8];
    float* out = (float*)d_out;

    const size_t Ntot = (size_t)in_sizes[0];   // 67108864 residual elements

    int*   flags = (int*)d_ws;                 // NCHAN ints (4 KB)
    float* part  = (float*)(flags + NCHAN);    // NCHAN*2 floats (8 KB)
    fx4*   res   = (fx4*)(out + 2 * BB);

    bitsel_init_kernel<<<1, NCHAN, 0, stream>>>(flags);

    bitsel_fused_kernel<<<NCHAN, TPB, 0, stream>>>(
        (const fx4*)x, gf, bits, wbits, Wl, bl, a1, a2, a3,
        out, res, flags, part, Ntot);
}